// Round 3
// baseline (262.276 us; speedup 1.0000x reference)
//
#include <hip/hip_runtime.h>
#include <cstdint>

#define C_    512
#define HW_   784
#define B_    64
#define BN_EPS 1e-5f

// Workspace layout:
//   [0, 32768)        : wbits   uint32[512][16]   (bit c%32 of word c/32 = 1 iff W[o][c] < 0)
//   [32768, 40960)    : params  float4[512]       {A2, C2, slope, bias}
//
// Math folding:
//   scale[o] = mean|W[o,:]| ; S = 512 - 2*P (P = popcount(a^wsign)) ; y = scale*S
//   bn = A*S + B2,  A = gamma*scale*r, B2 = beta - gamma*mean*r
//   t  = bn + x - shift = (-2A)*P + (512A + B2 - shift) + x = A2*P + C2 + x
//   out = max(t,0) + slope*min(t,0) + bias   (branchless RPReLU)
//
// Journal:
//   R1: nontemporal stores -> WRITE 100->238 MB + L3 eviction of x. Never again.
//   R2: xv[32] reg-cache across the barrier was DEFEATED by the compiler
//       (VGPR=28, it rematerialized the loads to stay under the 64-reg cap).
//       FETCH dropped 127->64 MB (reloads hit L2/L3) but dur 86.7->83.3 only:
//       latency, not traffic, is the cost. Phase-2 loads were consumed ~64 cy
//       after issue -> per-chunk ~400 cy s_waitcnt stall.
//   R3 (this): software-pipelined phase 2, look-ahead = 1 chunk of 8 outputs.
//       x-burst for chunk k issues BEFORE popcount of chunk k+1 (~550 cy of
//       independent VALU) and is consumed after it. Peak regs ~56 < 64 so the
//       8-wave/SIMD cap holds and the compiler can keep the schedule.

__global__ __launch_bounds__(64) void precompute_kernel(
    const float* __restrict__ W,
    const float* __restrict__ bn_gamma, const float* __restrict__ bn_beta,
    const float* __restrict__ bn_mean,  const float* __restrict__ bn_var,
    const float* __restrict__ pr_slope, const float* __restrict__ pr_shift,
    const float* __restrict__ pr_bias,
    uint32_t* __restrict__ wbits, float4* __restrict__ params)
{
    const int o    = blockIdx.x;
    const int lane = threadIdx.x;
    const float* wrow = W + (size_t)o * C_;

    // mean(|W[o,:]|): stride-64 partials + wave-64 butterfly
    float s = 0.f;
    for (int c = lane; c < C_; c += 64) s += fabsf(wrow[c]);
    for (int off = 32; off > 0; off >>= 1) s += __shfl_down(s, off, 64);

    // sign bits: lanes 0..15 each pack one 32-bit word
    if (lane < 16) {
        uint32_t m = 0;
        const int cbase = lane * 32;
        #pragma unroll
        for (int t = 0; t < 32; ++t) {
            if (wrow[cbase + t] < 0.f) m |= (1u << t);
        }
        wbits[o * 16 + lane] = m;
    }

    if (lane == 0) {
        float scale = s * (1.0f / (float)C_);
        float r  = rsqrtf(bn_var[o] + BN_EPS);
        float A  = bn_gamma[o] * scale * r;
        float A2 = -2.0f * A;
        float C2 = (float)C_ * A + bn_beta[o] - bn_gamma[o] * bn_mean[o] * r
                 - pr_shift[o];
        params[o] = make_float4(A2, C2, pr_slope[o], pr_bias[o]);
    }
}

// Block: (64 lanes) x (16 waves) = 1024 threads; grid = 784 blocks covering
// the 50,176 flattened (b,hw) pairs exactly. Wave jj handles channels
// [32jj, 32jj+32) for both binarize (phase 1) and outputs (phase 2).
// Residency: 2 blocks/CU, 784 blocks -> 1.53 rounds (76.6% fill) -- accepted
// as structural this round; the lever here is load-latency hiding.

// POPC(base_oo): popcounts for outputs [c0+base_oo, c0+base_oo+8) into dst[8].
#define POPC(base_oo, dst)                                                    \
    {                                                                         \
        _Pragma("unroll")                                                     \
        for (int oo = 0; oo < 8; ++oo) {                                      \
            const uint32_t* wr = wbits + (c0 + (base_oo) + oo) * 16;          \
            int p = 0;                                                        \
            _Pragma("unroll")                                                 \
            for (int w = 0; w < 16; ++w) p += __popc(a[w] ^ wr[w]);           \
            (dst)[oo] = p;                                                    \
        }                                                                     \
    }

// XLOAD(base_oo): issue the 8 residual-x loads for a chunk (deep burst).
#define XLOAD(base_oo, dst)                                                   \
    {                                                                         \
        _Pragma("unroll")                                                     \
        for (int t = 0; t < 8; ++t)                                           \
            (dst)[t] = xg[(size_t)(c0 + (base_oo) + t) * HW_];                \
    }

// EPI(base_oo): epilogue + store for a chunk (consumes P and xv).
#define EPI(base_oo, Psrc, xsrc)                                              \
    {                                                                         \
        _Pragma("unroll")                                                     \
        for (int oo = 0; oo < 8; ++oo) {                                      \
            const int o = c0 + (base_oo) + oo;                                \
            const float4 p = params[o];                                       \
            const float tv = fmaf(p.x, (float)(Psrc)[oo], p.y + (xsrc)[oo]);  \
            const float rv = fmaf(p.z, fminf(tv, 0.f), fmaxf(tv, 0.f) + p.w); \
            og[(size_t)o * HW_] = rv;                                         \
        }                                                                     \
    }

__global__ __launch_bounds__(1024, 8) void fused_kernel(
    const float* __restrict__ x, const float* __restrict__ rsign_bias,
    const uint32_t* __restrict__ wbits, const float4* __restrict__ params,
    float* __restrict__ out)
{
    // a-bit tile: 64 pair-rows x 16 words, stride 17 -> 2-way bank alias (free)
    __shared__ uint32_t abits[64 * 17];

    const int i  = threadIdx.x;                                   // pair lane (0..63)
    const int jj = __builtin_amdgcn_readfirstlane(threadIdx.y);   // wave-uniform (0..15)

    const uint32_t pair = (uint32_t)blockIdx.x * 64u + (uint32_t)i;
    const uint32_t b    = pair / 784u;          // magic-mul division
    const uint32_t hw   = pair - b * 784u;
    const size_t   base = (size_t)b * (C_ * HW_) + hw;
    const float*   xg   = x + base;

    const int c0 = jj * 32;                                       // wave-uniform

    // ---- Phase 1: binarize channels [c0, c0+32) -> one bit-word ----
    // 32-deep load burst, then consume: full MLP for the compulsory read.
    {
        float v[32];
        #pragma unroll
        for (int t = 0; t < 32; ++t)
            v[t] = xg[(size_t)(c0 + t) * HW_];
        uint32_t m = 0;
        #pragma unroll
        for (int t = 0; t < 32; ++t) {
            if (v[t] + rsign_bias[c0 + t] < 0.f) m |= (1u << t);  // bias: s_load
        }
        abits[i * 17 + jj] = m;
    }
    __syncthreads();

    // ---- Phase 2: software-pipelined, look-ahead = 1 chunk of 8 outputs ----
    uint32_t a[16];
    #pragma unroll
    for (int w = 0; w < 16; ++w) a[w] = abits[i * 17 + w];

    float* og = out + base;

    int   P[8], Pn[8];
    float xv[8], xvn[8];

    POPC(0,  P);              // chunk 0 popcounts (a live)
    XLOAD(0, xv);             // issue chunk-0 x burst
    POPC(8,  Pn);             // 256 VALU ops cover xv latency
    XLOAD(8, xvn);            // issue chunk-1 x burst
    EPI(0,  P,  xv);          // consume chunk 0 (loads are ~550 cy old)
    POPC(16, P);
    XLOAD(16, xv);
    EPI(8,  Pn, xvn);
    POPC(24, Pn);             // a dies after this
    XLOAD(24, xvn);
    EPI(16, P,  xv);
    EPI(24, Pn, xvn);
}

#undef POPC
#undef XLOAD
#undef EPI

extern "C" void kernel_launch(void* const* d_in, const int* in_sizes, int n_in,
                              void* d_out, int out_size, void* d_ws, size_t ws_size,
                              hipStream_t stream) {
    const float* x          = (const float*)d_in[0];
    const float* rsign_bias = (const float*)d_in[1];
    const float* W          = (const float*)d_in[2];
    const float* bn_gamma   = (const float*)d_in[3];
    const float* bn_beta    = (const float*)d_in[4];
    const float* bn_mean    = (const float*)d_in[5];
    const float* bn_var     = (const float*)d_in[6];
    const float* pr_slope   = (const float*)d_in[7];
    const float* pr_shift   = (const float*)d_in[8];
    const float* pr_bias    = (const float*)d_in[9];
    float* out = (float*)d_out;

    uint32_t* wbits  = (uint32_t*)d_ws;
    float4*   params = (float4*)((char*)d_ws + 32768);

    precompute_kernel<<<dim3(C_), dim3(64), 0, stream>>>(
        W, bn_gamma, bn_beta, bn_mean, bn_var, pr_slope, pr_shift, pr_bias,
        wbits, params);

    // 50176 (b,hw) pairs = 784 tiles of 64, zero waste; 1024-thr blocks,
    // 2 blocks/CU.
    fused_kernel<<<dim3(784), dim3(64, 16), 0, stream>>>(
        x, rsign_bias, wbits, params, out);
}

// Round 4
// 238.331 us; speedup vs baseline: 1.1005x; 1.1005x over previous
//
#include <hip/hip_runtime.h>
#include <cstdint>

#define C_    512
#define HW_   784
#define B_    64
#define BN_EPS 1e-5f

// Workspace layout:
//   [0, 32768)        : wbits   uint32[512][16]   (bit c%32 of word c/32 = 1 iff W[o][c] < 0)
//   [32768, 40960)    : params  float4[512]       {A2, C2, slope, bias}
//
// Math folding:
//   scale[o] = mean|W[o,:]| ; S = 512 - 2*P (P = popcount(a^wsign)) ; y = scale*S
//   bn = A*S + B2,  A = gamma*scale*r, B2 = beta - gamma*mean*r
//   t  = bn + x - shift = (-2A)*P + (512A + B2 - shift) + x = A2*P + C2 + x
//   out = max(t,0) + slope*min(t,0) + bias   (branchless RPReLU)
//
// Journal:
//   R1: nontemporal stores -> WRITE 100->238 MB + L3 eviction of x. Never again.
//   R2: xv[32] reg-cache defeated by regalloc under the 64-VGPR cap (VGPR=28,
//       loads rematerialized in phase 2). FETCH 127->64 MB but dur only -4%.
//   R3: software-pipelined phase 2 ALSO flattened by regalloc (VGPR=32); the
//       store/load interleave additionally thrashed L2 (FETCH 160, WRITE 169 MB).
//       dur 113 us. LESSON: under a 64-reg cap the compiler always collapses
//       multi-load-in-flight structure. Don't fight the scheduler; buy regs.
//   R4 (this): __launch_bounds__(1024,4) -> 128-reg budget. xv[32] held across
//       the barrier and PINNED via empty asm ("+v") so remat is illegal.
//       Phase 2 has ZERO global loads. Round quantization unchanged (76.6%
//       both at 8w and 4w/SIMD: 50176 pairs / 32768-resident vs /16384*2).

__global__ __launch_bounds__(64) void precompute_kernel(
    const float* __restrict__ W,
    const float* __restrict__ bn_gamma, const float* __restrict__ bn_beta,
    const float* __restrict__ bn_mean,  const float* __restrict__ bn_var,
    const float* __restrict__ pr_slope, const float* __restrict__ pr_shift,
    const float* __restrict__ pr_bias,
    uint32_t* __restrict__ wbits, float4* __restrict__ params)
{
    const int o    = blockIdx.x;
    const int lane = threadIdx.x;
    // Lane loads its 8 consecutive weights as 2x float4 (coalesced, 2 instrs;
    // replaces R0's 32 strided scalar loads for the sign pass).
    const float4* wrow4 = (const float4*)(W + (size_t)o * C_);
    const float4 u = wrow4[2 * lane];
    const float4 v = wrow4[2 * lane + 1];

    float s = fabsf(u.x) + fabsf(u.y) + fabsf(u.z) + fabsf(u.w)
            + fabsf(v.x) + fabsf(v.y) + fabsf(v.z) + fabsf(v.w);
    for (int off = 32; off > 0; off >>= 1) s += __shfl_down(s, off, 64);

    // 8-bit sign mask per lane (bit j = W[o, 8*lane+j] < 0)
    uint32_t m8 = (u.x < 0.f ? 1u : 0u)  | (u.y < 0.f ? 2u : 0u)
                | (u.z < 0.f ? 4u : 0u)  | (u.w < 0.f ? 8u : 0u)
                | (v.x < 0.f ? 16u : 0u) | (v.y < 0.f ? 32u : 0u)
                | (v.z < 0.f ? 64u : 0u) | (v.w < 0.f ? 128u : 0u);

    // word w = masks of lanes 4w..4w+3 (all lanes shuffle, lanes<16 store)
    const uint32_t g0 = __shfl(m8, 4 * lane + 0, 64);
    const uint32_t g1 = __shfl(m8, 4 * lane + 1, 64);
    const uint32_t g2 = __shfl(m8, 4 * lane + 2, 64);
    const uint32_t g3 = __shfl(m8, 4 * lane + 3, 64);
    if (lane < 16)
        wbits[o * 16 + lane] = g0 | (g1 << 8) | (g2 << 16) | (g3 << 24);

    if (lane == 0) {
        float scale = s * (1.0f / (float)C_);
        float r  = rsqrtf(bn_var[o] + BN_EPS);
        float A  = bn_gamma[o] * scale * r;
        float A2 = -2.0f * A;
        float C2 = (float)C_ * A + bn_beta[o] - bn_gamma[o] * bn_mean[o] * r
                 - pr_shift[o];
        params[o] = make_float4(A2, C2, pr_slope[o], pr_bias[o]);
    }
}

// Block: (64 lanes) x (16 waves) = 1024 threads; grid = 784 blocks covering
// the 50,176 flattened (b,hw) pairs exactly. Wave jj binarizes channels
// [32jj, 32jj+32) for its 64 pairs AND computes outputs for those channels;
// the residual x it needs in phase 2 is exactly what it loaded in phase 1.
// __launch_bounds__(1024, 4): 128-VGPR budget so xv[32]+a[16]+overhead (~70)
// fits WITHOUT remat. 1 block/CU resident (16 waves/CU). Phase 2 is
// global-load-free, so it needs no TLP; phase 1 has 32 loads/thread in
// flight x 4 waves/SIMD = 128 outstanding for the compulsory HBM read.
__global__ __launch_bounds__(1024, 4) void fused_kernel(
    const float* __restrict__ x, const float* __restrict__ rsign_bias,
    const uint32_t* __restrict__ wbits, const float4* __restrict__ params,
    float* __restrict__ out)
{
    // a-bit tile: 64 pair-rows x 16 words, stride 17 -> 2-way bank alias (free)
    __shared__ uint32_t abits[64 * 17];

    const int i  = threadIdx.x;                                   // pair lane (0..63)
    const int jj = __builtin_amdgcn_readfirstlane(threadIdx.y);   // wave-uniform (0..15)

    const uint32_t pair = (uint32_t)blockIdx.x * 64u + (uint32_t)i;
    const uint32_t b    = pair / 784u;          // magic-mul division
    const uint32_t hw   = pair - b * 784u;
    const size_t   base = (size_t)b * (C_ * HW_) + hw;
    const float*   xg   = x + base;

    const int c0 = jj * 32;                                       // wave-uniform

    // ---- Phase 1: load this wave's 32 channels ONCE, keep in registers ----
    float xv[32];
    #pragma unroll
    for (int t = 0; t < 32; ++t)
        xv[t] = xg[(size_t)(c0 + t) * HW_];

    uint32_t m = 0;
    #pragma unroll
    for (int t = 0; t < 32; ++t) {
        if (xv[t] + rsign_bias[c0 + t] < 0.f) m |= (1u << t);   // bias: s_load
    }
    abits[i * 17 + jj] = m;
    __syncthreads();

    // Pin xv in VGPRs: the empty asm "writes" each value, so the compiler
    // cannot legally rematerialize the global load past this point (the
    // R2/R3 failure mode). Compiles to zero instructions.
    #pragma unroll
    for (int t = 0; t < 32; ++t) asm volatile("" : "+v"(xv[t]));

    // ---- Phase 2: global-load-free. Bits from LDS, wbits/params via s_load,
    //      residual x from registers, plain stores (R1 lesson). ----
    uint32_t a[16];
    #pragma unroll
    for (int w = 0; w < 16; ++w) a[w] = abits[i * 17 + w];

    float* og = out + base;

    #pragma unroll
    for (int oo = 0; oo < 32; ++oo) {
        const int o = c0 + oo;                           // wave-uniform
        const uint32_t* wr = wbits + o * 16;             // s_load rows
        int P = 0;
        #pragma unroll
        for (int w = 0; w < 16; ++w) P += __popc(a[w] ^ wr[w]);

        const float4 p = params[o];
        const float t = fmaf(p.x, (float)P, p.y + xv[oo]);
        const float r = fmaf(p.z, fminf(t, 0.f), fmaxf(t, 0.f) + p.w);
        og[(size_t)o * HW_] = r;
    }
}

extern "C" void kernel_launch(void* const* d_in, const int* in_sizes, int n_in,
                              void* d_out, int out_size, void* d_ws, size_t ws_size,
                              hipStream_t stream) {
    const float* x          = (const float*)d_in[0];
    const float* rsign_bias = (const float*)d_in[1];
    const float* W          = (const float*)d_in[2];
    const float* bn_gamma   = (const float*)d_in[3];
    const float* bn_beta    = (const float*)d_in[4];
    const float* bn_mean    = (const float*)d_in[5];
    const float* bn_var     = (const float*)d_in[6];
    const float* pr_slope   = (const float*)d_in[7];
    const float* pr_shift   = (const float*)d_in[8];
    const float* pr_bias    = (const float*)d_in[9];
    float* out = (float*)d_out;

    uint32_t* wbits  = (uint32_t*)d_ws;
    float4*   params = (float4*)((char*)d_ws + 32768);

    precompute_kernel<<<dim3(C_), dim3(64), 0, stream>>>(
        W, bn_gamma, bn_beta, bn_mean, bn_var, pr_slope, pr_shift, pr_bias,
        wbits, params);

    // 50176 (b,hw) pairs = 784 tiles of 64, zero waste; 1024-thr blocks,
    // 1 block/CU (see launch_bounds rationale above).
    fused_kernel<<<dim3(784), dim3(64, 16), 0, stream>>>(
        x, rsign_bias, wbits, params, out);
}